// Round 7
// baseline (251.988 us; speedup 1.0000x reference)
//
#include <hip/hip_runtime.h>
#include <hip/hip_bf16.h>

#define B_ 2
#define C_ 20000
#define H_ 64
#define M_ 8
#define E_ 200000
#define P_ 3
#define EPS_ 1e-12f
#define ET_ (E_ / 64)   // edge tiles per batch = 3125

typedef __attribute__((ext_vector_type(8))) short short8;
typedef __attribute__((ext_vector_type(4))) float float4v;

__device__ __forceinline__ float silu_(float x) {
    return x / (1.f + __expf(-x));
}
__device__ __forceinline__ unsigned short f2b(float f) {
    unsigned u = __float_as_uint(f);
    unsigned r = (u + 0x7FFF + ((u >> 16) & 1)) >> 16;   // RNE fp32->bf16
    return (unsigned short)r;
}
__device__ __forceinline__ float b2f(unsigned short h) {
    return __uint_as_float(((unsigned)h) << 16);
}
__device__ __forceinline__ unsigned pk2u(float a, float b) {
    __hip_bfloat162 h = __float22bfloat162_rn(make_float2(a, b)); // v_cvt_pk_bf16_f32
    unsigned u; __builtin_memcpy(&u, &h, sizeof(u)); return u;
}

// bf16 B-fragment-swizzled weights (K multiples of 32; W1 rows 128..131 on VALU)
#define W1S_OFF 0
#define W2S_OFF 8192
#define P1S_OFF 12288
#define U1S_OFF 16384
#define U2S_OFF 24576
#define WBUF_ELEMS 28672

// combo_kernel block ranges (all parts independent)
#define NB_PREP   120                    // 28672 weight-frag elems
#define NB_FEATB  2500                   // B*C*64/4 = 640000 threads
#define NB_DESC   157                    // ceil(B*C/256)
#define NB_HIST   782                    // ceil(E/256)
#define NB_AGGZ   2500                   // zero aggf: B*C*64/4 float4
#define NB_PCPY   118                    // out_pos = pos: 30000 float4
#define NB_COMBO  (NB_PREP + NB_FEATB + NB_DESC + NB_HIST + NB_AGGZ + NB_PCPY)

__global__ __launch_bounds__(256) void combo_kernel(
    const float* __restrict__ W1, const float* __restrict__ W2,
    const float* __restrict__ P1, const float* __restrict__ U1,
    const float* __restrict__ U2, unsigned short* __restrict__ wbuf,
    const float* __restrict__ feat, unsigned short* __restrict__ featb,
    const float* __restrict__ pos, const int* __restrict__ cni,
    const float* __restrict__ mask, float* __restrict__ desc,
    const int* __restrict__ ei, int* __restrict__ cnt,
    float* __restrict__ aggf, float* __restrict__ out_pos)
{
    const int bid = blockIdx.x;
    if (bid < NB_PREP) {
        // ---- weight swizzle -> bf16 B-fragments
        int t = bid * 256 + threadIdx.x;
        if (t >= WBUF_ELEMS) return;
        const float* W; int e;
        if (t < W2S_OFF)      { W = W1; e = t; }
        else if (t < U1S_OFF) { W = (t < P1S_OFF) ? W2 : P1; e = (t < P1S_OFF) ? t - W2S_OFF : t - P1S_OFF; }
        else if (t < U2S_OFF) { W = U1; e = t - U1S_OFF; }
        else                  { W = U2; e = t - U2S_OFF; }
        int j = e & 7, lane = (e >> 3) & 63, nt = (e >> 9) & 3, kk = e >> 11;
        int k = kk * 32 + ((lane >> 4) * 8) + j;
        int n = nt * 16 + (lane & 15);
        wbuf[t] = f2b(W[k * 64 + n]);
    } else if (bid < NB_PREP + NB_FEATB) {
        // ---- features -> bf16 cache (coalesced)
        int t = (bid - NB_PREP) * 256 + threadIdx.x;   // < 640000 exactly
        float4 v = *(const float4*)&feat[(size_t)t * 4];
        *(uint2*)&featb[(size_t)t * 4] = make_uint2(pk2u(v.x, v.y), pk2u(v.z, v.w));
    } else if (bid < NB_PREP + NB_FEATB + NB_DESC) {
        // ---- per-(b,cell) descriptor: 8x(x,y,z,m) + centroid + own pos
        int tid = (bid - NB_PREP - NB_FEATB) * 256 + threadIdx.x;
        if (tid >= B_ * C_) return;
        int b = tid / C_, c = tid - b * C_;
        const float* pb = pos + (size_t)b * C_ * P_;
        float4* D = (float4*)(desc + (size_t)tid * 40);
        int4 n0 = *(const int4*)&cni[c*8];
        int4 n1 = *(const int4*)&cni[c*8 + 4];
        float4 m0 = *(const float4*)&mask[c*8];
        float4 m1 = *(const float4*)&mask[c*8 + 4];
        int ni[8] = {n0.x, n0.y, n0.z, n0.w, n1.x, n1.y, n1.z, n1.w};
        float mm[8] = {m0.x, m0.y, m0.z, m0.w, m1.x, m1.y, m1.z, m1.w};
        float sx = 0.f, sy = 0.f, sz = 0.f, sm = 0.f;
        #pragma unroll
        for (int m = 0; m < 8; ++m) {
            float x = pb[ni[m]*3+0], y = pb[ni[m]*3+1], z = pb[ni[m]*3+2];
            D[m] = make_float4(x, y, z, mm[m]);
            sx += x * mm[m]; sy += y * mm[m]; sz += z * mm[m]; sm += mm[m];
        }
        float inv = 1.f / fmaxf(sm, EPS_);
        D[8] = make_float4(sx * inv, sy * inv, sz * inv, sm);
        D[9] = make_float4(pb[c*3+0], pb[c*3+1], pb[c*3+2], 0.f);
    } else if (bid < NB_PREP + NB_FEATB + NB_DESC + NB_HIST) {
        // ---- dst histogram
        int e = (bid - NB_PREP - NB_FEATB - NB_DESC) * 256 + threadIdx.x;
        if (e >= E_) return;
        atomicAdd(&cnt[ei[E_ + e]], 1);
    } else if (bid < NB_PREP + NB_FEATB + NB_DESC + NB_HIST + NB_AGGZ) {
        // ---- zero aggf
        int t = (bid - NB_PREP - NB_FEATB - NB_DESC - NB_HIST) * 256 + threadIdx.x;
        ((float4*)aggf)[t] = make_float4(0.f, 0.f, 0.f, 0.f);
    } else {
        // ---- out_pos = pos
        int t = (bid - NB_PREP - NB_FEATB - NB_DESC - NB_HIST - NB_AGGZ) * 256 + threadIdx.x;
        if (t < (B_ * C_ * P_) / 4)
            ((float4*)out_pos)[t] = ((const float4*)pos)[t];
    }
}

// ---------------------------------------------------------------------------
// alloc: wave-scan + one atomic bump per wave -> cursor (segment order free)
// ---------------------------------------------------------------------------
__global__ __launch_bounds__(256) void alloc_kernel(
    const int* __restrict__ cnt, int* __restrict__ cursor, int* __restrict__ total)
{
    int idx = blockIdx.x * 256 + threadIdx.x;
    int lane = threadIdx.x & 63;
    int v = (idx < C_) ? cnt[idx] : 0;
    int inc = v;
    #pragma unroll
    for (int s = 1; s < 64; s <<= 1) {
        int n = __shfl_up(inc, s);
        if (lane >= s) inc += n;
    }
    int wtot = __shfl(inc, 63);
    int base = 0;
    if (lane == 0) base = atomicAdd(total, wtot);
    base = __shfl(base, 0);
    if (idx < C_) cursor[idx] = base + inc - v;
}

__global__ __launch_bounds__(256) void scatter_kernel(
    const int* __restrict__ ei, int* __restrict__ cursor,
    int* __restrict__ ssrc, int* __restrict__ sdst)
{
    int e = blockIdx.x * 256 + threadIdx.x;
    if (e >= E_) return;
    int s = ei[e], d = ei[E_ + e];
    int slot = atomicAdd(&cursor[d], 1);
    ssrc[slot] = s;
    sdst[slot] = d;
}

// ---------------------------------------------------------------------------
// Edge kernel: fused geometry + 3 MFMA MLP stages + in-wave segmented
// aggregation. 4 independent waves/block, barrier-free wave-private LDS.
// __launch_bounds__(256,4): 128-VGPR budget -> no spills (R6 at 64 VGPR
// spilled the geometry working set; phantom VALU ~5x source count).
// ---------------------------------------------------------------------------
__global__ __launch_bounds__(256, 4) void edge_kernel(
    const unsigned short* __restrict__ featb,
    const int* __restrict__ ssrc, const int* __restrict__ sdst,
    const float* __restrict__ desc,
    const unsigned short* __restrict__ wbuf, const float* __restrict__ W1,
    const float* __restrict__ b1, const float* __restrict__ b2,
    const float* __restrict__ pb1, const float* __restrict__ P2,
    const float* __restrict__ pb2,
    float* __restrict__ aggf, float* __restrict__ out_pos)
{
    __shared__ unsigned short lds[4 * 3328];   // 26624 B

    const int tid  = threadIdx.x;
    const int w    = tid >> 6;
    const int lane = tid & 63;
    const int q    = lane >> 4;
    const int l16  = lane & 15;
    const int w16  = w * 16;

    const int tile = blockIdx.x;
    const int b    = tile / ET_;
    const int i0   = (tile - b * ET_) * 64;
    const int s_l  = ssrc[i0 + lane];
    const int d_l  = sdst[i0 + lane];
    const unsigned short* fb = featb + (size_t)b * C_ * H_;

    unsigned short* Xw = lds + w * 3328;
    unsigned short* Hw = Xw + 2176;
    unsigned short* Mw = Xw;   // alias: X dead before M written (dep chain)

    // ================= geometry (edge = w16 + l16, j-split across quads) =====
    const int sg = __shfl(s_l, w16 + l16);
    const int dg = __shfl(d_l, w16 + l16);
    const float4* Ds = (const float4*)(desc + ((size_t)b * C_ + sg) * 40);
    const float4* Dd = (const float4*)(desc + ((size_t)b * C_ + dg) * 40);

    const float INFV = __builtin_inff();
    float4 S[8];
    float a_i[8], infm_i[8], rowmin[8];
    #pragma unroll
    for (int i = 0; i < 8; ++i) {
        S[i] = Ds[i];
        a_i[i] = S[i].x*S[i].x + S[i].y*S[i].y + S[i].z*S[i].z + EPS_;
        infm_i[i] = (S[i].w > 0.f) ? 0.f : INFV;
        rowmin[i] = INFV;
    }
    float pair = 0.f, hyx = 0.f;
    #pragma unroll
    for (int jj = 0; jj < 2; ++jj) {
        float4 Dj = Dd[q*2 + jj];
        float dp2 = Dj.x*Dj.x + Dj.y*Dj.y + Dj.z*Dj.z;
        float infm_j = (Dj.w > 0.f) ? 0.f : INFV;
        float colmin = INFV, psum = 0.f;
        #pragma unroll
        for (int i = 0; i < 8; ++i) {
            float cr = S[i].x*Dj.x + S[i].y*Dj.y + S[i].z*Dj.z;
            float t  = (a_i[i] + dp2) - 2.f*cr;
            float dd = sqrtf(fmaxf(t, EPS_));        // == sqrt(max(q,0)+EPS)
            psum = fmaf(dd, S[i].w, psum);
            rowmin[i] = fminf(rowmin[i], dd + infm_j);
            colmin    = fminf(colmin,    dd + infm_i[i]);
        }
        pair = fmaf(Dj.w, psum, pair);
        hyx = fmaxf(hyx, (Dj.w > 0.f) ? colmin : 0.f);
    }
    pair += __shfl_xor(pair, 16);  pair += __shfl_xor(pair, 32);
    hyx = fmaxf(hyx, __shfl_xor(hyx, 16));  hyx = fmaxf(hyx, __shfl_xor(hyx, 32));
    #pragma unroll
    for (int i = 0; i < 8; ++i) {
        rowmin[i] = fminf(rowmin[i], __shfl_xor(rowmin[i], 16));
        rowmin[i] = fminf(rowmin[i], __shfl_xor(rowmin[i], 32));
    }
    float hxy = 0.f;
    #pragma unroll
    for (int i = 0; i < 8; ++i)
        hxy = fmaxf(hxy, (S[i].w > 0.f) ? rowmin[i] : 0.f);
    float4 Sc = Ds[8], Dc = Dd[8];
    float cdx = Sc.x - Dc.x, cdy = Sc.y - Dc.y, cdz = Sc.z - Dc.z;
    float4 Sp = Ds[9], Dp = Dd[9];
    const float relx = Sp.x - Dp.x, rely = Sp.y - Dp.y, relz = Sp.z - Dp.z;
    const float ivx = sqrtf(relx*relx + rely*rely + relz*relz);  // dist
    const float ivy = pair;                                      // pairwise
    const float ivz = sqrtf(cdx*cdx + cdy*cdy + cdz*cdz);        // centroid
    const float ivw = fmaxf(hxy, hyx);                           // hausdorff

    // ================= stage X = [h_src | h_dst] from bf16 cache =============
    const int rr4 = lane >> 4, c4 = lane & 15;
    #pragma unroll
    for (int it = 0; it < 4; ++it) {
        int rloc = it * 4 + rr4;
        int r = w16 + rloc;
        int sr = __shfl(s_l, r);
        int dr = __shfl(d_l, r);
        uint2 vs = *(const uint2*)&fb[(size_t)sr * 64 + c4 * 4];
        uint2 vd = *(const uint2*)&fb[(size_t)dr * 64 + c4 * 4];
        *(uint2*)&Xw[rloc*136 + c4*4]      = vs;
        *(uint2*)&Xw[rloc*136 + 64 + c4*4] = vd;
    }

    // ================= layer 1: MFMA k<128 + fp32 invariant tail =============
    float4v acc[4];
    #pragma unroll
    for (int nt = 0; nt < 4; ++nt) {
        float bv = b1[nt*16 + l16];
        acc[nt] = (float4v){bv, bv, bv, bv};
    }
    #pragma unroll
    for (int kk = 0; kk < 4; ++kk) {
        short8 a = *(const short8*)&Xw[l16*136 + kk*32 + q*8];
        #pragma unroll
        for (int nt = 0; nt < 4; ++nt) {
            short8 bf = *(const short8*)&wbuf[W1S_OFF + (((kk*4 + nt)*64) + lane) * 8];
            acc[nt] = __builtin_amdgcn_mfma_f32_16x16x32_bf16(a, bf, acc[nt], 0, 0, 0);
        }
    }
    float4 iv[4];
    #pragma unroll
    for (int i = 0; i < 4; ++i) {
        int r = q*4 + i;
        iv[i] = make_float4(__shfl(ivx, r), __shfl(ivy, r),
                            __shfl(ivz, r), __shfl(ivw, r));
    }
    #pragma unroll
    for (int nt = 0; nt < 4; ++nt) {
        float wa = W1[128*64 + nt*16 + l16];
        float wb = W1[129*64 + nt*16 + l16];
        float wc = W1[130*64 + nt*16 + l16];
        float wd = W1[131*64 + nt*16 + l16];
        #pragma unroll
        for (int i = 0; i < 4; ++i)
            acc[nt][i] += iv[i].x*wa + iv[i].y*wb + iv[i].z*wc + iv[i].w*wd;
    }
    #pragma unroll
    for (int nt = 0; nt < 4; ++nt)
        #pragma unroll
        for (int i = 0; i < 4; ++i)
            Hw[(q*4 + i)*72 + nt*16 + l16] = f2b(silu_(acc[nt][i]));

    // ================= layer 2 -> messages ===================================
    float4v mac[4];
    #pragma unroll
    for (int nt = 0; nt < 4; ++nt) {
        float bv = b2[nt*16 + l16];
        mac[nt] = (float4v){bv, bv, bv, bv};
    }
    #pragma unroll
    for (int kk = 0; kk < 2; ++kk) {
        short8 a = *(const short8*)&Hw[l16*72 + kk*32 + q*8];
        #pragma unroll
        for (int nt = 0; nt < 4; ++nt) {
            short8 bf = *(const short8*)&wbuf[W2S_OFF + (((kk*4 + nt)*64) + lane) * 8];
            mac[nt] = __builtin_amdgcn_mfma_f32_16x16x32_bf16(a, bf, mac[nt], 0, 0, 0);
        }
    }
    #pragma unroll
    for (int nt = 0; nt < 4; ++nt)
        #pragma unroll
        for (int i = 0; i < 4; ++i)
            Mw[(q*4 + i)*72 + nt*16 + l16] = f2b(mac[nt][i]);

    // ================= gate: wt = tanh(silu(M @ P1 + pb1) @ P2 + pb2) ========
    float4v gac[4];
    #pragma unroll
    for (int nt = 0; nt < 4; ++nt) {
        float bv = pb1[nt*16 + l16];
        gac[nt] = (float4v){bv, bv, bv, bv};
    }
    #pragma unroll
    for (int kk = 0; kk < 2; ++kk) {
        short8 a = *(const short8*)&Mw[l16*72 + kk*32 + q*8];
        #pragma unroll
        for (int nt = 0; nt < 4; ++nt) {
            short8 bf = *(const short8*)&wbuf[P1S_OFF + (((kk*4 + nt)*64) + lane) * 8];
            gac[nt] = __builtin_amdgcn_mfma_f32_16x16x32_bf16(a, bf, gac[nt], 0, 0, 0);
        }
    }
    float p2v[4];
    #pragma unroll
    for (int nt = 0; nt < 4; ++nt) p2v[nt] = P2[nt*16 + l16];
    const float pb2v = pb2[0];

    #pragma unroll
    for (int i = 0; i < 4; ++i) {
        float p = 0.f;
        #pragma unroll
        for (int nt = 0; nt < 4; ++nt) p += silu_(gac[nt][i]) * p2v[nt];
        p += __shfl_xor(p, 8);
        p += __shfl_xor(p, 4);
        p += __shfl_xor(p, 2);
        p += __shfl_xor(p, 1);
        float wt = tanhf(p + pb2v);
        // park wt in spare fp32-aligned columns 64..65 of the message row
        if (l16 == 0) *(float*)&Mw[(q*4 + i)*72 + 64] = wt;
    }

    float* aggB = aggf + (size_t)b * C_ * 64;
    float* opB  = out_pos + (size_t)b * C_ * 3;

    // ================= position update: lane-parallel per-edge atomics ======
    // lane l16 (any quad) holds edge w16+l16's rel and wt.
    float wtl = *(const float*)&Mw[l16*72 + 64];
    float gx = wtl * relx, gy = wtl * rely, gz = wtl * relz;
    int e3 = lane / 3;                 // lanes 0..47 -> (edge, component)
    int c3 = lane - e3 * 3;
    float sx = __shfl(gx, e3);
    float sy = __shfl(gy, e3);
    float sz = __shfl(gz, e3);
    float val = (c3 == 0) ? sx : (c3 == 1) ? sy : sz;
    int de = __shfl(d_l, w16 + e3);
    if (lane < 48) atomicAdd(&opB[(size_t)de * 3 + c3], val);

    // ================= in-wave segmented message aggregation ================
    float mrow[16];
    #pragma unroll
    for (int rr = 0; rr < 16; ++rr) mrow[rr] = b2f(Mw[rr*72 + lane]);

    int dprev = __shfl(d_l, w16);
    float colacc = 0.f;
    #pragma unroll
    for (int rr = 0; rr < 16; ++rr) {
        int dcur = __shfl(d_l, w16 + rr);          // wave-uniform
        if (dcur != dprev) {                       // uniform branch
            atomicAdd(&aggB[(size_t)dprev * 64 + lane], colacc);
            colacc = 0.f;
            dprev = dcur;
        }
        colacc += mrow[rr];
    }
    atomicAdd(&aggB[(size_t)dprev * 64 + lane], colacc);
}

// ---------------------------------------------------------------------------
// Node update via MFMA, barrier-free wave-private strips.
// ---------------------------------------------------------------------------
__global__ __launch_bounds__(256, 4) void node_kernel(
    const float* __restrict__ feat, const unsigned short* __restrict__ featb,
    const float* __restrict__ aggf, const float* __restrict__ deg,
    const unsigned short* __restrict__ wbuf,
    const float* __restrict__ ub1, const float* __restrict__ ub2,
    float* __restrict__ out_feat)
{
    __shared__ unsigned short lds[4 * 3328];

    const int tid  = threadIdx.x;
    const int w    = tid >> 6;
    const int lane = tid & 63;
    const int q    = lane >> 4;
    const int l16  = lane & 15;
    const int g0   = blockIdx.x * 64;

    unsigned short* Xw = lds + w * 3328;
    unsigned short* Hw = Xw + 2176;

    const int rr4 = lane >> 4, c4 = lane & 15;
    #pragma unroll
    for (int it = 0; it < 4; ++it) {
        int rloc = it * 4 + rr4;
        int g = g0 + w*16 + rloc;
        int gc = (g >= C_) ? g - C_ : g;
        float sc = 1.f / fmaxf(deg[gc], 1.f);
        uint2  vf = *(const uint2*)&featb[(size_t)g * 64 + c4 * 4];
        float4 va = *(const float4*)&aggf[(size_t)g * 64 + c4 * 4];
        *(uint2*)&Xw[rloc*136 + c4*4]      = vf;
        *(uint2*)&Xw[rloc*136 + 64 + c4*4] =
            make_uint2(pk2u(va.x*sc, va.y*sc), pk2u(va.z*sc, va.w*sc));
    }

    float4v acc[4];
    #pragma unroll
    for (int nt = 0; nt < 4; ++nt) {
        float bv = ub1[nt*16 + l16];
        acc[nt] = (float4v){bv, bv, bv, bv};
    }
    #pragma unroll
    for (int kk = 0; kk < 4; ++kk) {
        short8 a = *(const short8*)&Xw[l16*136 + kk*32 + q*8];
        #pragma unroll
        for (int nt = 0; nt < 4; ++nt) {
            short8 bf = *(const short8*)&wbuf[U1S_OFF + (((kk*4 + nt)*64) + lane) * 8];
            acc[nt] = __builtin_amdgcn_mfma_f32_16x16x32_bf16(a, bf, acc[nt], 0, 0, 0);
        }
    }
    #pragma unroll
    for (int nt = 0; nt < 4; ++nt)
        #pragma unroll
        for (int i = 0; i < 4; ++i)
            Hw[(q*4 + i)*72 + nt*16 + l16] = f2b(silu_(acc[nt][i]));

    float4v oac[4];
    #pragma unroll
    for (int nt = 0; nt < 4; ++nt) {
        float bv = ub2[nt*16 + l16];
        oac[nt] = (float4v){bv, bv, bv, bv};
    }
    #pragma unroll
    for (int kk = 0; kk < 2; ++kk) {
        short8 a = *(const short8*)&Hw[l16*72 + kk*32 + q*8];
        #pragma unroll
        for (int nt = 0; nt < 4; ++nt) {
            short8 bf = *(const short8*)&wbuf[U2S_OFF + (((kk*4 + nt)*64) + lane) * 8];
            oac[nt] = __builtin_amdgcn_mfma_f32_16x16x32_bf16(a, bf, oac[nt], 0, 0, 0);
        }
    }
    #pragma unroll
    for (int nt = 0; nt < 4; ++nt)
        #pragma unroll
        for (int i = 0; i < 4; ++i) {
            size_t idx = (size_t)(g0 + w*16 + q*4 + i) * 64 + nt*16 + l16;
            out_feat[idx] = feat[idx] + oac[nt][i];
        }
}

extern "C" void kernel_launch(void* const* d_in, const int* in_sizes, int n_in,
                              void* d_out, int out_size, void* d_ws, size_t ws_size,
                              hipStream_t stream) {
    const float* feat = (const float*)d_in[0];
    const float* pos  = (const float*)d_in[1];
    const int*   ei   = (const int*)d_in[2];
    const float* deg  = (const float*)d_in[3];
    const int*   cni  = (const int*)d_in[4];
    const float* mask = (const float*)d_in[5];
    const float* W1   = (const float*)d_in[6];
    const float* b1   = (const float*)d_in[7];
    const float* W2   = (const float*)d_in[8];
    const float* b2   = (const float*)d_in[9];
    const float* P1   = (const float*)d_in[10];
    const float* pb1  = (const float*)d_in[11];
    const float* P2   = (const float*)d_in[12];
    const float* pb2  = (const float*)d_in[13];
    const float* U1   = (const float*)d_in[14];
    const float* ub1  = (const float*)d_in[15];
    const float* U2   = (const float*)d_in[16];
    const float* ub2  = (const float*)d_in[17];

    float* out_feat = (float*)d_out;                       // B*C*H
    float* out_pos  = out_feat + (size_t)B_ * C_ * H_;     // B*C*P

    // workspace layout (~24 MB)
    float* desc = (float*)d_ws;                                  // B*C*40 fp32
    float* aggf = desc + (size_t)B_ * C_ * 40;                   // B*C*64 fp32
    unsigned short* featb = (unsigned short*)(aggf + (size_t)B_ * C_ * 64); // B*C*64
    unsigned short* wbuf  = featb + (size_t)B_ * C_ * 64;        // 28672
    int* cnt    = (int*)(wbuf + WBUF_ELEMS);                     // C
    int* total  = cnt + C_;                                      // 1
    int* cursor = total + 1;                                     // C
    int* ssrc   = cursor + C_;                                   // E
    int* sdst   = ssrc + E_;                                     // E

    hipMemsetAsync(cnt, 0, (C_ + 1) * sizeof(int), stream);      // cnt + total

    combo_kernel<<<NB_COMBO, 256, 0, stream>>>(
        W1, W2, P1, U1, U2, wbuf, feat, featb, pos, cni, mask, desc, ei, cnt,
        aggf, out_pos);

    alloc_kernel<<<(C_ + 255) / 256, 256, 0, stream>>>(cnt, cursor, total);
    scatter_kernel<<<(E_ + 255) / 256, 256, 0, stream>>>(ei, cursor, ssrc, sdst);

    edge_kernel<<<B_ * ET_, 256, 0, stream>>>(
        featb, ssrc, sdst, desc, wbuf, W1, b1, b2, pb1, P2, pb2, aggf, out_pos);

    node_kernel<<<(B_ * C_) / 64, 256, 0, stream>>>(
        feat, featb, aggf, deg, wbuf, ub1, ub2, out_feat);
}